// Round 3
// baseline (184.329 us; speedup 1.0000x reference)
//
#include <hip/hip_runtime.h>

// MFHawkes: B=4, L=2048, K=100000, D=64
// Algebraic collapse (validated R1/R2, absmax 0.0):
//   lam_i   = |ab * exp(-ab*t_i) * (e_i . P_i) + u_i| + 1e-6,
//             P_i = sum_{j<i} e_j * exp(ab*t_j) * m_j       (D-vector prefix sum)
//   out[b]  = sum_i [-log(lam_i) + u_i*horizon] + (sum_i e_i) . V,
//             V   = sum_j e_j * (1 - exp(-ab*(t_last - t_j)))
//
// R3: all-register single kernel, CL=32 -> 256 blocks (1 per CU). Gathered
// rows live in VGPRs (lane = dim); the dot e_i.P_i is a per-row 6-step
// butterfly reduce -> zero LDS, zero __syncthreads. Cross-chunk prefix via
// chained-scan flags in ws (poison 0xAAAAAAAA != 1, so flags are "unset"
// at launch). Block (b, NC-1) writes out[b] directly -> no memset/atomics.

#define BB 4
#define LL 2048
#define DD 64
#define CL 32            // chunk length (rows per block)
#define NC (LL / CL)     // 64 chunks per batch -> 256 blocks total

#define LOADF(p)     __hip_atomic_load((p), __ATOMIC_RELAXED, __HIP_MEMORY_SCOPE_AGENT)
#define STOREF(p, v) __hip_atomic_store((p), (v), __ATOMIC_RELAXED, __HIP_MEMORY_SCOPE_AGENT)

__global__ __launch_bounds__(64) void fused_hawkes(
    const int* __restrict__ ids, const float* __restrict__ times,
    const float* __restrict__ mask, const float* __restrict__ emb,
    const float* __restrict__ u_table, const float* __restrict__ beta,
    float* __restrict__ S, float* __restrict__ Ep, float* __restrict__ Vp,
    float* __restrict__ Ctr, int* __restrict__ flag1, int* __restrict__ flag2,
    float* __restrict__ out)
{
    const int blk = blockIdx.x;
    const int b = blk / NC, c = blk % NC;
    const int lane = threadIdx.x;          // 0..63 = dim d
    const int row  = lane & (CL - 1);      // lanes 32..63 duplicate rows 0..31
    const int j0 = c * CL;
    const int rec = b * NC + c;

    const float ab = fabsf(beta[0]);
    const float tl = times[b * LL + LL - 1] * 1e-4f;
    const float t1 = times[b * LL + 1] * 1e-4f;
    const float horizon = tl - t1;
    const float ce = expf(-ab * tl);       // exp(-ab * t_last)

    // per-lane row scalars (row = j0 + (lane&31)), broadcast via shfl
    const int   myid = ids  [b * LL + j0 + row];
    const float myt  = times[b * LL + j0 + row] * 1e-4f;
    const float mym  = mask [b * LL + j0 + row];
    const float myuk = fabsf(u_table[myid]);
    const float wlane  = expf(ab * myt);   // exp(ab * t_j) in [1, 1.105]
    const float wmlane = wlane * mym;

    // ---- gather: 32 emb rows -> registers (max MLP: loads issued first) ----
    float e[CL];
#pragma unroll
    for (int j = 0; j < CL; ++j) {
        const int id = __shfl(myid, j);
        e[j] = emb[(long)id * DD + lane];  // 256B row, coalesced over lanes
    }

    float s = 0.f, ep = 0.f, vp = 0.f;
#pragma unroll
    for (int j = 0; j < CL; ++j) {
        const float wm = __shfl(wmlane, j);
        const float w  = __shfl(wlane,  j);
        s  += e[j] * wm;                   // f_j = e_j * exp(ab t_j) * m_j
        ep += e[j];
        vp += e[j] * (1.f - ce * w);
    }

    // ---- publish chunk record, release flag1 ------------------------------
    STOREF(&S [rec * DD + lane], s);
    STOREF(&Ep[rec * DD + lane], ep);
    STOREF(&Vp[rec * DD + lane], vp);
    __threadfence();
    if (lane == 0)
        __hip_atomic_store(&flag1[rec], 1, __ATOMIC_RELEASE, __HIP_MEMORY_SCOPE_AGENT);

    // ---- lookback: exclusive cross-chunk offset ---------------------------
    for (int cc = 0; cc < c; ++cc)
        while (__hip_atomic_load(&flag1[b * NC + cc], __ATOMIC_ACQUIRE,
                                 __HIP_MEMORY_SCOPE_AGENT) != 1)
            __builtin_amdgcn_s_sleep(1);

    float run = 0.f;
    for (int cc = 0; cc < c; ++cc)
        run += LOADF(&S[(b * NC + cc) * DD + lane]);

    // ---- scan + dot, all in registers (lane = dim) ------------------------
    // per row j: dot = sum_d e_j[d]*P[d] (butterfly), then P += f_j
    float total = 0.f;
#pragma unroll
    for (int j = 0; j < CL; ++j) {
        float d = e[j] * run;
#pragma unroll
        for (int off = 32; off > 0; off >>= 1)
            d += __shfl_xor(d, off);       // d now = e_j . P_j on all lanes
        const float tj = __shfl(myt,  j);
        const float uj = __shfl(myuk, j);
        const float lam = fabsf(ab * expf(-ab * tj) * d + uj) + 1e-6f;
        total += -logf(lam) + uj * horizon;   // identical across lanes
        run += e[j] * __shfl(wmlane, j);
    }

    if (c != NC - 1) {
        if (lane == 0) {
            STOREF(&Ctr[rec], total);
            __threadfence();
            __hip_atomic_store(&flag2[rec], 1, __ATOMIC_RELEASE, __HIP_MEMORY_SCOPE_AGENT);
        }
    } else {
        // summer block: collect other chunks' scalars + (sum e).(V) term
        for (int cc = 0; cc < NC - 1; ++cc)
            while (__hip_atomic_load(&flag2[b * NC + cc], __ATOMIC_ACQUIRE,
                                     __HIP_MEMORY_SCOPE_AGENT) != 1)
                __builtin_amdgcn_s_sleep(1);

        float et = 0.f, vt = 0.f;
#pragma unroll 8
        for (int cc = 0; cc < NC; ++cc) {   // flag1 of all cc acquired above
            et += LOADF(&Ep[(b * NC + cc) * DD + lane]);
            vt += LOADF(&Vp[(b * NC + cc) * DD + lane]);
        }
        float v = et * vt;                  // per-dim product, reduce below
        if (lane < NC - 1) v += LOADF(&Ctr[b * NC + lane]);
#pragma unroll
        for (int off = 32; off > 0; off >>= 1)
            v += __shfl_xor(v, off);
        if (lane == 0)
            out[b] = v + total;             // sole writer, plain store
    }
}

// ---------------------------------------------------------------------------
extern "C" void kernel_launch(void* const* d_in, const int* in_sizes, int n_in,
                              void* d_out, int out_size, void* d_ws, size_t ws_size,
                              hipStream_t stream)
{
    const int*   ids     = (const int*)  d_in[0];
    const float* times   = (const float*)d_in[1];
    const float* mask    = (const float*)d_in[2];
    const float* emb     = (const float*)d_in[3];
    const float* u_table = (const float*)d_in[4];
    const float* beta    = (const float*)d_in[5];
    float* outp = (float*)d_out;

    float* ws    = (float*)d_ws;
    float* S     = ws;                       // BB*NC*DD = 16384 floats
    float* Ep    = S   + BB * NC * DD;       // 16384
    float* Vp    = Ep  + BB * NC * DD;       // 16384
    float* Ctr   = Vp  + BB * NC * DD;       // BB*NC = 256
    int*   flag1 = (int*)(Ctr + BB * NC);    // 256
    int*   flag2 = flag1 + BB * NC;          // 256

    fused_hawkes<<<BB * NC, 64, 0, stream>>>(ids, times, mask, emb, u_table,
                                             beta, S, Ep, Vp, Ctr,
                                             flag1, flag2, outp);
}

// Round 4
// 96.054 us; speedup vs baseline: 1.9190x; 1.9190x over previous
//
#include <hip/hip_runtime.h>

// MFHawkes: B=4, L=2048, K=100000, D=64
// Algebraic collapse (validated R1-R3, absmax 0.0):
//   lam_i   = |ab * exp(-ab*t_i) * (e_i . P_i) + u_i| + 1e-6,
//             P_i = sum_{j<i} e_j * exp(ab*t_j) * m_j       (D-vector prefix sum)
//   out[b]  = sum_i [-log(lam_i) + u_i*horizon] + (sum_i e_i) . V,
//             V   = sum_j e_j * (1 - exp(-ab*(t_last - t_j)))
//
// R4: three stream-ordered dispatches, ZERO cross-block flags/atomics
// (R3 post-mortem: agent-scope spin chains cost ~110us of idle; stream
// ordering is free). No Ebuf staging (k2 re-gathers emb, L2/L3-hot).
// No memset: k2 writes per-chunk scalars (folding ep_chunk . V_total),
// k3 sums 32 scalars per batch -> out[b].

#define BB 4
#define LL 2048
#define DD 64
#define CL 64            // chunk length
#define NC (LL / CL)     // 32 chunks per batch -> 128 blocks

// ---------------------------------------------------------------------------
// k1: per-chunk partial sums S (scan seed), Ep (sum e), Vp (integral vec).
// ---------------------------------------------------------------------------
__global__ __launch_bounds__(64) void k1_sums(
    const int* __restrict__ ids, const float* __restrict__ times,
    const float* __restrict__ mask, const float* __restrict__ emb,
    const float* __restrict__ beta,
    float* __restrict__ S, float* __restrict__ Ep, float* __restrict__ Vp)
{
    const int blk = blockIdx.x;
    const int b = blk / NC, c = blk % NC;
    const int lane = threadIdx.x;          // dim d
    const int j0 = c * CL;
    const int rec = b * NC + c;

    const float ab = fabsf(beta[0]);
    const float tl = times[b * LL + LL - 1] * 1e-4f;
    const float ce = expf(-ab * tl);       // exp(-ab * t_last)

    const int   myid = ids  [b * LL + j0 + lane];
    const float myt  = times[b * LL + j0 + lane] * 1e-4f;
    const float mym  = mask [b * LL + j0 + lane];
    const float wlane  = expf(ab * myt);
    const float wmlane = wlane * mym;

    float s = 0.f, ep = 0.f, vp = 0.f;
#pragma unroll 16
    for (int jj = 0; jj < CL; ++jj) {
        const int   id = __shfl(myid, jj);
        const float w  = __shfl(wlane,  jj);
        const float wm = __shfl(wmlane, jj);
        const float e  = emb[(long)id * DD + lane];   // 256B row, coalesced
        s  += e * wm;
        ep += e;
        vp += e * (1.f - ce * w);
    }
    S [rec * DD + lane] = s;
    Ep[rec * DD + lane] = ep;
    Vp[rec * DD + lane] = vp;
}

// ---------------------------------------------------------------------------
// k2: per-chunk scan + dot + epilogue -> one scalar per chunk (Ctr).
// Folds ep_chunk . V_total (V complete because k1 finished).
// ---------------------------------------------------------------------------
__global__ __launch_bounds__(64) void k2_scan(
    const int* __restrict__ ids, const float* __restrict__ times,
    const float* __restrict__ mask, const float* __restrict__ emb,
    const float* __restrict__ u_table, const float* __restrict__ beta,
    const float* __restrict__ S, const float* __restrict__ Ep,
    const float* __restrict__ Vp, float* __restrict__ Ctr)
{
    __shared__ float E [CL][DD + 1];   // +1 pad: 2-way alias only (free)
    __shared__ float LP[CL][DD + 1];
    __shared__ float wm[CL];

    const int blk = blockIdx.x;
    const int b = blk / NC, c = blk % NC;
    const int lane = threadIdx.x;
    const int j0 = c * CL;
    const int rec = b * NC + c;

    const float ab = fabsf(beta[0]);
    const float tl = times[b * LL + LL - 1] * 1e-4f;
    const float t1 = times[b * LL + 1] * 1e-4f;
    const float horizon = tl - t1;

    const int   myid = ids  [b * LL + j0 + lane];
    const float myt  = times[b * LL + j0 + lane] * 1e-4f;
    const float mym  = mask [b * LL + j0 + lane];
    const float myuk = fabsf(u_table[myid]);
    wm[lane] = expf(ab * myt) * mym;

    // V_total[d] and exclusive chunk offset O[d]  (small hot ws reads)
    float vt = 0.f;
#pragma unroll 8
    for (int cc = 0; cc < NC; ++cc)
        vt += Vp[(b * NC + cc) * DD + lane];
    float run = 0.f;
    for (int cc = 0; cc < c; ++cc)
        run += S[(b * NC + cc) * DD + lane];
    const float epc = Ep[rec * DD + lane];

    // gather emb rows -> LDS tile (L2/L3-hot after k1)
#pragma unroll 16
    for (int jj = 0; jj < CL; ++jj) {
        const int id = __shfl(myid, jj);
        E[jj][lane] = emb[(long)id * DD + lane];
    }
    __syncthreads();

    // intra-chunk exclusive scan (lane = dim)
#pragma unroll 8
    for (int i = 0; i < CL; ++i) {
        LP[i][lane] = run;
        run += E[i][lane] * wm[i];         // wm[i]: LDS broadcast (free)
    }
    __syncthreads();

    // dot phase (lane = row): e_i . P_i
    float acc = 0.f;
#pragma unroll
    for (int k = 0; k < DD; ++k)
        acc += E[lane][k] * LP[lane][k];

    const float lam = fabsf(ab * expf(-ab * myt) * acc + myuk) + 1e-6f;
    // per-lane: row contrib + this chunk's share of (sum e).V
    float v = -logf(lam) + myuk * horizon + epc * vt;
#pragma unroll
    for (int off = 32; off > 0; off >>= 1)
        v += __shfl_xor(v, off);
    if (lane == 0)
        Ctr[rec] = v;
}

// ---------------------------------------------------------------------------
// k3: sum 32 chunk scalars per batch -> out[b]. 4 blocks, no memset needed.
// ---------------------------------------------------------------------------
__global__ __launch_bounds__(64) void k3_final(
    const float* __restrict__ Ctr, float* __restrict__ out)
{
    const int b = blockIdx.x;
    const int lane = threadIdx.x;
    float v = (lane < NC) ? Ctr[b * NC + lane] : 0.f;
#pragma unroll
    for (int off = 32; off > 0; off >>= 1)
        v += __shfl_xor(v, off);
    if (lane == 0)
        out[b] = v;
}

// ---------------------------------------------------------------------------
extern "C" void kernel_launch(void* const* d_in, const int* in_sizes, int n_in,
                              void* d_out, int out_size, void* d_ws, size_t ws_size,
                              hipStream_t stream)
{
    const int*   ids     = (const int*)  d_in[0];
    const float* times   = (const float*)d_in[1];
    const float* mask    = (const float*)d_in[2];
    const float* emb     = (const float*)d_in[3];
    const float* u_table = (const float*)d_in[4];
    const float* beta    = (const float*)d_in[5];
    float* outp = (float*)d_out;

    float* ws  = (float*)d_ws;
    float* S   = ws;                     // BB*NC*DD = 8192 floats
    float* Ep  = S  + BB * NC * DD;      // 8192
    float* Vp  = Ep + BB * NC * DD;      // 8192
    float* Ctr = Vp + BB * NC * DD;      // BB*NC = 128

    k1_sums<<<BB * NC, 64, 0, stream>>>(ids, times, mask, emb, beta, S, Ep, Vp);
    k2_scan<<<BB * NC, 64, 0, stream>>>(ids, times, mask, emb, u_table, beta,
                                        S, Ep, Vp, Ctr);
    k3_final<<<BB, 64, 0, stream>>>(Ctr, outp);
}

// Round 5
// 95.174 us; speedup vs baseline: 1.9368x; 1.0092x over previous
//
#include <hip/hip_runtime.h>

// MFHawkes: B=4, L=2048, K=100000, D=64
// Algebraic collapse (validated R1-R4, absmax 0.0):
//   lam_i   = |ab * exp(-ab*t_i) * (e_i . P_i) + u_i| + 1e-6,
//             P_i = sum_{j<i} e_j * exp(ab*t_j) * m_j       (D-vector prefix sum)
//   out[b]  = sum_i [-log(lam_i) + u_i*horizon] + (sum_i e_i) . V,
//             V   = sum_j e_j * (1 - exp(-ab*(t_last - t_j)))
//
// R5: two stream-ordered dispatches (R4 minus one launch). k1 also zeroes
// out[] (runs before k2, stream-ordered); k2 folds the final reduction via
// one atomicAdd per chunk. No flags, no cross-block spin (R3 lesson), no
// Ebuf staging (k2 re-gathers emb L2/L3-hot, R4 lesson). Measured floor is
// the harness's 256MiB ws-poison fill (~44us @ 97% HBM) + input restores.

#define BB 4
#define LL 2048
#define DD 64
#define CL 64            // chunk length
#define NC (LL / CL)     // 32 chunks per batch -> 128 blocks

// ---------------------------------------------------------------------------
// k1: per-chunk partial sums S (scan seed), Ep (sum e), Vp (integral vec).
// Block 0 zero-inits out[0..BB).
// ---------------------------------------------------------------------------
__global__ __launch_bounds__(64) void k1_sums(
    const int* __restrict__ ids, const float* __restrict__ times,
    const float* __restrict__ mask, const float* __restrict__ emb,
    const float* __restrict__ beta,
    float* __restrict__ S, float* __restrict__ Ep, float* __restrict__ Vp,
    float* __restrict__ out)
{
    const int blk = blockIdx.x;
    const int b = blk / NC, c = blk % NC;
    const int lane = threadIdx.x;          // dim d
    const int j0 = c * CL;
    const int rec = b * NC + c;

    if (blk == 0 && lane < BB)
        out[lane] = 0.f;                   // consumed by k2's atomicAdd

    const float ab = fabsf(beta[0]);
    const float tl = times[b * LL + LL - 1] * 1e-4f;
    const float ce = expf(-ab * tl);       // exp(-ab * t_last)

    const int   myid = ids  [b * LL + j0 + lane];
    const float myt  = times[b * LL + j0 + lane] * 1e-4f;
    const float mym  = mask [b * LL + j0 + lane];
    const float wlane  = expf(ab * myt);
    const float wmlane = wlane * mym;

    float s = 0.f, ep = 0.f, vp = 0.f;
#pragma unroll 16
    for (int jj = 0; jj < CL; ++jj) {
        const int   id = __shfl(myid, jj);
        const float w  = __shfl(wlane,  jj);
        const float wm = __shfl(wmlane, jj);
        const float e  = emb[(long)id * DD + lane];   // 256B row, coalesced
        s  += e * wm;
        ep += e;
        vp += e * (1.f - ce * w);
    }
    S [rec * DD + lane] = s;
    Ep[rec * DD + lane] = ep;
    Vp[rec * DD + lane] = vp;
}

// ---------------------------------------------------------------------------
// k2: per-chunk scan + dot + epilogue; folds ep_chunk . V_total and adds
// one scalar per chunk into out[b] (zeroed by k1, stream-ordered).
// ---------------------------------------------------------------------------
__global__ __launch_bounds__(64) void k2_scan(
    const int* __restrict__ ids, const float* __restrict__ times,
    const float* __restrict__ mask, const float* __restrict__ emb,
    const float* __restrict__ u_table, const float* __restrict__ beta,
    const float* __restrict__ S, const float* __restrict__ Ep,
    const float* __restrict__ Vp, float* __restrict__ out)
{
    __shared__ float E [CL][DD + 1];   // +1 pad: 2-way alias only (free)
    __shared__ float LP[CL][DD + 1];
    __shared__ float wm[CL];

    const int blk = blockIdx.x;
    const int b = blk / NC, c = blk % NC;
    const int lane = threadIdx.x;
    const int j0 = c * CL;
    const int rec = b * NC + c;

    const float ab = fabsf(beta[0]);
    const float tl = times[b * LL + LL - 1] * 1e-4f;
    const float t1 = times[b * LL + 1] * 1e-4f;
    const float horizon = tl - t1;

    const int   myid = ids  [b * LL + j0 + lane];
    const float myt  = times[b * LL + j0 + lane] * 1e-4f;
    const float mym  = mask [b * LL + j0 + lane];
    const float myuk = fabsf(u_table[myid]);
    wm[lane] = expf(ab * myt) * mym;

    // V_total[d] and exclusive chunk offset O[d]  (small hot ws reads)
    float vt = 0.f;
#pragma unroll 8
    for (int cc = 0; cc < NC; ++cc)
        vt += Vp[(b * NC + cc) * DD + lane];
    float run = 0.f;
    for (int cc = 0; cc < c; ++cc)
        run += S[(b * NC + cc) * DD + lane];
    const float epc = Ep[rec * DD + lane];

    // gather emb rows -> LDS tile (L2/L3-hot after k1)
#pragma unroll 16
    for (int jj = 0; jj < CL; ++jj) {
        const int id = __shfl(myid, jj);
        E[jj][lane] = emb[(long)id * DD + lane];
    }
    __syncthreads();

    // intra-chunk exclusive scan (lane = dim)
#pragma unroll 8
    for (int i = 0; i < CL; ++i) {
        LP[i][lane] = run;
        run += E[i][lane] * wm[i];         // wm[i]: LDS broadcast (free)
    }
    __syncthreads();

    // dot phase (lane = row): e_i . P_i
    float acc = 0.f;
#pragma unroll
    for (int k = 0; k < DD; ++k)
        acc += E[lane][k] * LP[lane][k];

    const float lam = fabsf(ab * expf(-ab * myt) * acc + myuk) + 1e-6f;
    // per-lane: row contrib + this chunk's share of (sum e).V
    float v = -logf(lam) + myuk * horizon + epc * vt;
#pragma unroll
    for (int off = 32; off > 0; off >>= 1)
        v += __shfl_xor(v, off);
    if (lane == 0)
        atomicAdd(&out[b], v);             // 32 adders/batch, negligible
}

// ---------------------------------------------------------------------------
extern "C" void kernel_launch(void* const* d_in, const int* in_sizes, int n_in,
                              void* d_out, int out_size, void* d_ws, size_t ws_size,
                              hipStream_t stream)
{
    const int*   ids     = (const int*)  d_in[0];
    const float* times   = (const float*)d_in[1];
    const float* mask    = (const float*)d_in[2];
    const float* emb     = (const float*)d_in[3];
    const float* u_table = (const float*)d_in[4];
    const float* beta    = (const float*)d_in[5];
    float* outp = (float*)d_out;

    float* ws  = (float*)d_ws;
    float* S   = ws;                     // BB*NC*DD = 8192 floats
    float* Ep  = S  + BB * NC * DD;      // 8192
    float* Vp  = Ep + BB * NC * DD;      // 8192

    k1_sums<<<BB * NC, 64, 0, stream>>>(ids, times, mask, emb, beta,
                                        S, Ep, Vp, outp);
    k2_scan<<<BB * NC, 64, 0, stream>>>(ids, times, mask, emb, u_table, beta,
                                        S, Ep, Vp, outp);
}